// Round 14
// baseline (218.822 us; speedup 1.0000x reference)
//
#include <hip/hip_runtime.h>
#include <cstdint>

typedef unsigned int u32;
typedef unsigned long long u64;
typedef unsigned short u16;
typedef unsigned char u8;

#define HM_H 960
#define HM_W 1280
#define HM_N (HM_H*HM_W)       /* 1228800 */
#define BATCH 4
#define CAND 8192
#define KPT 1024
#define NCELL 19200            /* 120*160 */

/* workspace layout (bytes) */
#define WS_HIST  0x0           /* 4*65536 u32 (20-bit hist uses first 12453/batch) */
#define WS_META  0x200000      /* 4*64 u32 */
#define WS_CAND  0x200400      /* 4*8192 u64 */
#define WS_EQ    0x240400      /* 4*8192 u64 (true keys) -> 0x280400 */
#define WS_SEL   0x280400      /* 4*1024 u32 */
#define WS_CM    0x284400      /* 4*19200 f32 */
#define WS_CS    0x2CF400      /* 4*19200 f64 */
#define WS_SPOT  0x365400      /* 4*8192 u32 packed (y<<16|x) */
#define WS_BST   0x385400      /* 4*4804 u32 bucket CSR starts */
#define WS_BLST  0x398040      /* 4*8192 u16 bucket entries (rank) */
#define WS_CNT   0x3A8040      /* 4*8192 u32 conflict count */
#define WS_STAT  0x3C8040      /* 4*8192 u8 status */
#define WS_CLST  0x3D0040      /* 4*8192*12 u16 conflict lists -> 0x4D0040 */
#define WS_CAND2 0x4D0040      /* 4*8192 u64 merge ping-pong */

/* meta fields per batch (stride 64 u32):
   3 V20 (absolute top-20 pivot), 4 countGt, 5 needEq, 6 gtCtr, 7 eqCtr */

#define FLOOR_BITS 0x3C75C28Fu
#define B20_0 0x3C75Cu         /* FLOOR_BITS>>12 */
#define NB20  12453            /* 0x3F800 - 0x3C75C + 1 */

__device__ inline double pixval64(const float* __restrict__ semi, const float* __restrict__ cm,
                                  const double* __restrict__ cs, int b, u32 idx){
  u32 y = idx / HM_W, x = idx - y*HM_W;
  u32 hc = y>>3, wc = x>>3, ch = ((y&7)<<3) | (x&7);
  float logit = semi[(((size_t)b*65 + ch)*120 + hc)*160 + wc];
  int cid = b*NCELL + (int)(hc*160 + wc);
  return exp((double)logit - (double)cm[cid]) / cs[cid];
}

/* 8-threads-per-cell softmax+depth2space FUSED with the 20-bit histogram
   (values histogrammed from registers, LDS-private, terminal flush). */
__global__ __launch_bounds__(256) void k_heatmap(const float* __restrict__ semi, float* __restrict__ hm,
                          float* __restrict__ cm, double* __restrict__ cs, u32* __restrict__ hist){
  extern __shared__ u32 lh[];        /* NB20 u32 */
  for (int i=threadIdx.x;i<NB20;i+=256) lh[i]=0;
  __syncthreads();
  int tid = blockIdx.x*256 + threadIdx.x;
  int cell = tid >> 3, sub = tid & 7;
  int wc = cell % 160; int hc = (cell/160) % 120; int b = cell / NCELL;
  const float* p = semi + (size_t)b*65*NCELL + hc*160 + wc;
  float r[8];
  #pragma unroll
  for (int i=0;i<8;i++) r[i] = p[(size_t)(sub*8+i)*NCELL];
  float extra = (sub==7) ? p[(size_t)64*NCELL] : -3.0e38f;
  float m = extra;
  #pragma unroll
  for (int i=0;i<8;i++) m = fmaxf(m, r[i]);
  m = fmaxf(m, __shfl_xor(m,1,64));
  m = fmaxf(m, __shfl_xor(m,2,64));
  m = fmaxf(m, __shfl_xor(m,4,64));
  double S = 0.0;
  #pragma unroll
  for (int i=0;i<8;i++) S += exp((double)r[i] - (double)m);
  if (sub==7) S += exp((double)extra - (double)m);
  S += __shfl_xor(S,1,64);
  S += __shfl_xor(S,2,64);
  S += __shfl_xor(S,4,64);
  if (sub==0){ cm[cell]=m; cs[cell]=S; }
  float* out = hm + ((size_t)b*HM_H + hc*8 + sub)*HM_W + wc*8;
  float o[8];
  #pragma unroll
  for (int i=0;i<8;i++) o[i] = (float)(exp((double)r[i] - (double)m) / S);
  *reinterpret_cast<float4*>(out)     = make_float4(o[0],o[1],o[2],o[3]);
  *reinterpret_cast<float4*>(out + 4) = make_float4(o[4],o[5],o[6],o[7]);
  #pragma unroll
  for (int i=0;i<8;i++){
    u32 bs = __float_as_uint(o[i]);
    if (bs>=FLOOR_BITS){ u32 bi=(bs>>12)-B20_0; if(bi>=NB20)bi=NB20-1; atomicAdd(&lh[bi],1u); }
  }
  __syncthreads();
  u32* h = hist + b*65536;
  for (int i=threadIdx.x;i<NB20;i+=256){
    u32 c=lh[i]; if (c) atomicAdd(&h[i], c);
  }
}

/* single-phase 20-bit radix pivot: find bin where top-suffix crosses K */
__global__ void k_reduce(const u32* __restrict__ hist, u32* __restrict__ meta){
  int b = blockIdx.x;
  const u32* h = hist + b*65536;
  u32* mb = meta + b*64;
  const u32 K = (u32)CAND;
  int t = threadIdx.x;
  __shared__ u32 suf[1024];
  u32 s = 0;
  #pragma unroll
  for (int i=0;i<16;i++){ int bin = t*16+i; if (bin < NB20) s += h[bin]; }
  suf[t]=s; __syncthreads();
  for (int off=1; off<1024; off<<=1){
    u32 add = (t+off<1024) ? suf[t+off] : 0u;
    u32 nv2 = suf[t] + add;
    __syncthreads();
    suf[t]=nv2; __syncthreads();
  }
  u32 total = suf[0];
  u32 cumAbove = (t<1023) ? suf[t+1] : 0u;
  bool found = (cumAbove < K) && (cumAbove + s >= K);
  if (found){
    u32 cum = cumAbove; int bin = 0; u32 cA = cumAbove;
    for (int i=15;i>=0;i--){
      int bb = t*16+i; if (bb >= NB20) continue;
      u32 c = h[bb];
      if (cum + c >= K){ bin = bb; cA = cum; break; }
      cum += c;
    }
    mb[3] = B20_0 + (u32)bin;
    mb[4] = cA;
    mb[5] = K - cA;
  }
  if (t==0 && total < K){
    mb[3] = B20_0;
    u32 cA = total - h[0];
    mb[4] = cA;
    mb[5] = K - cA;
  }
}

/* block-chunked compaction vs 20-bit pivot: gt entries (true keys) to cand,
   pivot-bin entries (true keys) to eqk. */
#define CB_CAP 4800
#define EQ_CAP 2048
__global__ __launch_bounds__(256) void k_compact(const float* __restrict__ hm, u32* __restrict__ meta,
                          u64* __restrict__ cand, u64* __restrict__ eqk){
  __shared__ u32 pixb[CB_CAP];
  __shared__ u32 bsb[CB_CAP];
  __shared__ u64 eqb[EQ_CAP];
  __shared__ u32 cnt, ecnt, gbase, ebase;
  int b = blockIdx.x >> 8;
  int chunk = blockIdx.x & 255;
  if (threadIdx.x==0){ cnt=0u; ecnt=0u; }
  __syncthreads();
  u32 V20 = meta[b*64+3];
  const float4* src = (const float4*)(hm + (size_t)b*HM_N);
  int per = (HM_N/4)/256;
  int start = chunk*per;
  for (int i=start+(int)threadIdx.x; i<start+per; i+=256){
    float4 v = src[i];
    u32 pix = (u32)i*4u;
    u32 bs4[4];
    bs4[0]=__float_as_uint(v.x); bs4[1]=__float_as_uint(v.y);
    bs4[2]=__float_as_uint(v.z); bs4[3]=__float_as_uint(v.w);
    #pragma unroll
    for (int c2=0;c2<4;c2++){
      u32 bs = bs4[c2];
      u32 t20 = bs>>12;
      if (t20 > V20){ u32 p = atomicAdd(&cnt,1u); pixb[p]=pix+(u32)c2; bsb[p]=bs; }
      else if (t20 == V20 && bs >= FLOOR_BITS){
        u32 e = atomicAdd(&ecnt,1u);
        if (e < EQ_CAP) eqb[e] = (((u64)(~bs))<<32)|(u64)(pix+(u32)c2);
      }
    }
  }
  __syncthreads();
  if (threadIdx.x==0){
    gbase = cnt  ? atomicAdd(&meta[b*64+6], cnt)  : 0u;
    ebase = ecnt ? atomicAdd(&meta[b*64+7], ecnt) : 0u;
  }
  __syncthreads();
  u32 c0=cnt, e0=ecnt, gb=gbase, eb=ebase;
  if (e0 > EQ_CAP) e0 = EQ_CAP;
  for (u32 i=threadIdx.x; i<c0; i+=256){
    u32 s2 = gb+i;
    if (s2 < CAND) cand[(size_t)b*CAND+s2] = (((u64)(~bsb[i]))<<32)|(u64)pixb[i];
  }
  for (u32 i=threadIdx.x; i<e0; i+=256){
    u32 s2 = eb+i;
    if (s2 < CAND) eqk[(size_t)b*CAND+s2] = eqb[i];
  }
}

/* parallel eq-set selection: bitonic-sort up to 1024 pivot-bin keys
   (f32 desc, idx asc), f64 tie-cleanup, emit top needEq TRUE keys. */
__global__ __launch_bounds__(256) void k_eqprep(const u32* __restrict__ meta, u64* __restrict__ cand,
                         const u64* __restrict__ eqk,
                         const float* __restrict__ semi, const float* __restrict__ cm,
                         const double* __restrict__ cs){
  __shared__ u64 sk[1024];
  int b = blockIdx.x, t = threadIdx.x;
  const u32* mb = meta + b*64;
  u32 cA = mb[4], needEq = mb[5];
  u32 E = mb[7]; u32 n = E > 1024u ? 1024u : E;
  for (int i=t;i<1024;i+=256) sk[i] = (i < (int)n) ? eqk[(size_t)b*CAND+i] : ~0ull;
  __syncthreads();
  for (int k2=2;k2<=1024;k2<<=1)
    for (int j=k2>>1;j>0;j>>=1){
      int lj = __ffs(j)-1;
      for (int p=t; p<512; p+=256){
        int i = ((p >> lj) << (lj+1)) | (p & (j-1));
        int l = i | j;
        bool up = ((i & k2)==0);
        u64 a=sk[i], c=sk[l];
        if ((a>c)==up){ sk[i]=c; sk[l]=a; }
      }
      __syncthreads();
    }
  for (int pass=0; pass<8; pass++){
    int par = pass & 1;
    for (int q=t; q<512; q+=256){
      int p = par + 2*q;
      if (p+1 < 1024){
        u64 a = sk[p], c = sk[p+1];
        u32 ha = (u32)(a>>32), hc2 = (u32)(c>>32);
        if (ha == hc2 && ha != 0xFFFFFFFFu){
          double va = pixval64(semi, cm, cs, b, (u32)a);
          double vc = pixval64(semi, cm, cs, b, (u32)c);
          if (va < vc || (va == vc && (u32)a > (u32)c)){ sk[p]=c; sk[p+1]=a; }
        }
      }
    }
    __syncthreads();
  }
  for (u32 r=t; r<needEq; r+=256){
    u64 key = (r < n) ? sk[r] : ~0ull;
    u32 s2 = cA + r;
    if (s2 < CAND) cand[(size_t)b*CAND + s2] = key;
  }
}

/* local bitonic sort of a 2048-key segment (16 blocks = 4 batch x 4 seg). */
__global__ __launch_bounds__(512,1) void k_sortloc(u64* __restrict__ cand){
  __shared__ u64 sk[2048];
  int blk = blockIdx.x;
  int b = blk >> 2, seg = blk & 3;
  int t = threadIdx.x;
  int lane = t & 63, w = t >> 6;
  int base = w*256 + lane;
  u64* cb = cand + (size_t)b*CAND + seg*2048;
  u64 E[4];
  #pragma unroll
  for (int m=0;m<4;m++) E[m] = cb[base + m*64];

  for (int k2=2; k2<=2048; k2<<=1){
    int j = k2>>1;
    if (j >= 256){
      __syncthreads();
      #pragma unroll
      for (int m=0;m<4;m++) sk[base + m*64] = E[m];
      __syncthreads();
      for (; j>=256; j>>=1){
        int lj = __ffs(j)-1;
        for (int p=t; p<1024; p+=512){
          int i = ((p >> lj) << (lj+1)) | (p & (j-1));
          int l = i | j;
          bool up = ((i & k2)==0);
          u64 a=sk[i], c=sk[l];
          if ((a>c)==up){ sk[i]=c; sk[l]=a; }
        }
        __syncthreads();
      }
      #pragma unroll
      for (int m=0;m<4;m++) E[m] = sk[base + m*64];
      j = 128;
    }
    for (; j>=64; j>>=1){
      int mm = j>>6;
      #pragma unroll
      for (int m=0;m<4;m++){
        if ((m & mm)==0){
          int i = base + m*64;
          bool up = ((i & k2)==0);
          u64 a=E[m], c=E[m|mm];
          if ((a>c)==up){ E[m]=c; E[m|mm]=a; }
        }
      }
    }
    for (; j>=1; j>>=1){
      bool low0 = ((lane & j)==0);
      #pragma unroll
      for (int m=0;m<4;m++){
        int i = base + m*64;
        bool up = ((i & k2)==0);
        bool keepmin = (low0==up);
        u64 P = (u64)__shfl_xor((long long)E[m], j, 64);
        u64 mn = E[m]<P ? E[m] : P;
        u64 mx = E[m]<P ? P : E[m];
        E[m] = keepmin ? mn : mx;
      }
    }
  }
  #pragma unroll
  for (int m=0;m<4;m++) cb[base + m*64] = E[m];
}

/* stable parallel merge of sorted runs L -> 2L (merge-path, whole chip). */
__global__ __launch_bounds__(256) void k_merge(const u64* __restrict__ src, u64* __restrict__ dst, int L){
  int tid = blockIdx.x*256 + (int)threadIdx.x;
  if (tid >= BATCH*CAND) return;
  int b = tid >> 13;
  int e = tid & (CAND-1);
  int pairBase = (e / (2*L)) * (2*L);
  int off = e - pairBase;
  const u64* A = src + ((size_t)b<<13) + pairBase;
  const u64* B = A + L;
  bool inA = off < L;
  int i = inA ? off : off - L;
  u64 key = inA ? A[i] : B[i];
  const u64* O = inA ? B : A;
  int lo = 0, hi = L;
  if (inA){
    while (lo < hi){ int mid=(lo+hi)>>1; if (O[mid] < key) lo=mid+1; else hi=mid; }
  } else {
    while (lo < hi){ int mid=(lo+hi)>>1; if (O[mid] <= key) lo=mid+1; else hi=mid; }
  }
  dst[((size_t)b<<13) + pairBase + i + lo] = key;
}

/* f64 tie-cleanup + FUSED NMS stage 1 (spot + bucket CSR) from LDS. */
#define NBX 80
#define NBY 60
#define NBK (NBX*NBY)
#define BSTSTRIDE 4804
__global__ __launch_bounds__(1024,1) void k_sortfix(const u64* __restrict__ cand,
                       const float* __restrict__ semi, const float* __restrict__ cm,
                       const double* __restrict__ cs,
                       u32* __restrict__ spot, u32* __restrict__ bstG, u16* __restrict__ blistG){
  __shared__ u32 bcnt[NBK];
  __shared__ u32 bst[NBK];
  __shared__ u32 tsum[1024];
  extern __shared__ u64 sk[];
  int b = blockIdx.x, t = threadIdx.x;
  const u64* cb = cand + (size_t)b*CAND;
  for (int i=t;i<CAND;i+=1024) sk[i]=cb[i];
  for (int i=t;i<NBK;i+=1024) bcnt[i]=0;
  __syncthreads();
  for (int pass=0; pass<8; pass++){
    int par = pass & 1;
    for (int q=t; q<CAND/2; q+=1024){
      int p = par + 2*q;
      if (p+1 < CAND){
        u64 a = sk[p], c = sk[p+1];
        u32 ha = (u32)(a>>32), hc2 = (u32)(c>>32);
        if (ha == hc2 && ha != 0xFFFFFFFFu){
          double va = pixval64(semi, cm, cs, b, (u32)a);
          double vc = pixval64(semi, cm, cs, b, (u32)c);
          if (va < vc || (va == vc && (u32)a > (u32)c)){ sk[p]=c; sk[p+1]=a; }
        }
      }
    }
    __syncthreads();
  }
  for (int r=t;r<CAND;r+=1024){
    u32 idx = (u32)sk[r];
    u32 p;
    if (idx != 0xFFFFFFFFu){
      u32 y = idx/HM_W, x = idx - y*HM_W;
      p = (y<<16)|x;
      atomicAdd(&bcnt[(y>>4)*NBX+(x>>4)], 1u);
    } else p = 0xFFFFFFFFu;
    spot[(size_t)b*CAND+r] = p;
  }
  __syncthreads();
  u32 lsum=0;
  int base5 = t*5;
  if (base5 < NBK){
    #pragma unroll
    for (int j2=0;j2<5;j2++){ int ix=base5+j2; if (ix<NBK) lsum += bcnt[ix]; }
  }
  tsum[t]=lsum;
  __syncthreads();
  for (int off=1; off<1024; off<<=1){
    u32 add = (t>=off)? tsum[t-off] : 0u;
    __syncthreads();
    tsum[t] += add;
    __syncthreads();
  }
  if (base5 < NBK){
    u32 run = (t==0)?0u:tsum[t-1];
    #pragma unroll
    for (int j2=0;j2<5;j2++){
      int ix=base5+j2; if (ix<NBK){ u32 c=bcnt[ix]; bst[ix]=run; run+=c; }
    }
  }
  __syncthreads();
  for (int i=t;i<NBK;i+=1024){ bcnt[i]=bst[i]; bstG[(size_t)b*BSTSTRIDE+i]=bst[i]; }
  if (t==0) bstG[(size_t)b*BSTSTRIDE+NBK] = tsum[1023];
  __syncthreads();
  for (int r=t;r<CAND;r+=1024){
    u32 idx = (u32)sk[r];
    if (idx != 0xFFFFFFFFu){
      u32 y = idx/HM_W, x = idx - y*HM_W;
      u32 bu = (y>>4)*NBX + (x>>4);
      u32 slot = atomicAdd(&bcnt[bu],1u);
      blistG[(size_t)b*CAND+slot] = (u16)r;
    }
  }
}

/* NMS stage 2: per-candidate earlier-rank conflict lists (whole chip) */
#define CLCAP 12
__global__ __launch_bounds__(256) void k_nconf(const u32* __restrict__ spot, const u32* __restrict__ bstG,
                                               const u16* __restrict__ blistG, u32* __restrict__ cntG,
                                               u8* __restrict__ statG, u16* __restrict__ clistG){
  int b = blockIdx.x >> 5;
  int r = (blockIdx.x & 31)*256 + (int)threadIdx.x;
  const u32* sp = spot + (size_t)b*CAND;
  u32 p = sp[r];
  if (p == 0xFFFFFFFFu){ statG[(size_t)b*CAND+r]=2; return; }
  int y=(int)(p>>16), x=(int)(p&0xFFFFu);
  int by=y>>4, bx=x>>4;
  const u32* bs = bstG + (size_t)b*BSTSTRIDE;
  const u16* bl = blistG + (size_t)b*CAND;
  u16* cl = clistG + ((size_t)b*CAND + r)*CLCAP;
  int cnt=0; bool heavy=false;
  for (int dy=-1; dy<=1; dy++){
    int yy=by+dy; if (yy<0||yy>=NBY) continue;
    for (int dx=-1; dx<=1; dx++){
      int xx=bx+dx; if (xx<0||xx>=NBX) continue;
      int bu=yy*NBX+xx;
      int s=(int)bs[bu], e=(int)bs[bu+1];
      for (int q=s;q<e;q++){
        int j = (int)bl[q];
        if (j >= r) continue;
        u32 pj = sp[j];
        int ady = y-(int)(pj>>16); ady = ady<0?-ady:ady;
        int adx = x-(int)(pj&0xFFFFu); adx = adx<0?-adx:adx;
        if (ady<=4 && adx<=4){
          if (cnt < CLCAP) cl[cnt++] = (u16)j;
          else heavy = true;
        }
      }
    }
  }
  if (heavy){ cntG[(size_t)b*CAND+r]=0xFFFFFFFFu; statG[(size_t)b*CAND+r]=0; }
  else { cntG[(size_t)b*CAND+r]=(u32)cnt; statG[(size_t)b*CAND+r] = (cnt==0)?1:0; }
}

/* NMS stage 3: worklist fixed point + selection */
__global__ __launch_bounds__(1024,1) void k_nresolve(const u32* __restrict__ spot, const u32* __restrict__ bstG,
                                                     const u16* __restrict__ blistG, const u32* __restrict__ cntG,
                                                     u8* __restrict__ statG, const u16* __restrict__ clistG,
                                                     u32* __restrict__ sel){
  __shared__ u8 sstat[CAND];
  __shared__ u16 wl[2][CAND];
  __shared__ u32 wcnt[2];
  __shared__ u32 wpass[256];
  __shared__ u32 wpre[256];
  int b = blockIdx.x, t = threadIdx.x;
  const u32* sp = spot + (size_t)b*CAND;
  if (t<2) wcnt[t]=0;
  __syncthreads();
  for (int r=t;r<CAND;r+=1024){
    u8 st = statG[(size_t)b*CAND+r];
    sstat[r]=st;
    if (st==0){ u32 w=atomicAdd(&wcnt[0],1u); wl[0][w]=(u16)r; }
  }
  __syncthreads();
  int cur=0;
  for (int round=0; round<8192; ++round){
    int n = (int)wcnt[cur];
    if (n==0) break;
    int nx = cur^1;
    for (int i=t;i<n;i+=1024){
      int r = (int)wl[cur][i];
      u32 c = cntG[(size_t)b*CAND+r];
      bool supp=false, blocked=false;
      if (c==0xFFFFFFFFu){
        u32 p = sp[r];
        int y=(int)(p>>16), x=(int)(p&0xFFFFu);
        int by=y>>4, bx=x>>4;
        const u32* bs = bstG + (size_t)b*BSTSTRIDE;
        const u16* bl = blistG + (size_t)b*CAND;
        for (int dy=-1; dy<=1 && !supp; dy++){
          int yy=by+dy; if (yy<0||yy>=NBY) continue;
          for (int dx=-1; dx<=1 && !supp; dx++){
            int xx=bx+dx; if (xx<0||xx>=NBX) continue;
            int bu=yy*NBX+xx;
            int s=(int)bs[bu], e=(int)bs[bu+1];
            for (int q=s;q<e;q++){
              int j = (int)bl[q];
              if (j >= r) continue;
              u32 pj = sp[j];
              int ady = y-(int)(pj>>16); ady = ady<0?-ady:ady;
              int adx = x-(int)(pj&0xFFFFu); adx = adx<0?-adx:adx;
              if (ady<=4 && adx<=4){
                u8 st = sstat[j];
                if (st==1){ supp=true; break; }
                if (st==0) blocked=true;
              }
            }
          }
        }
      } else {
        const u16* cl = clistG + ((size_t)b*CAND + r)*CLCAP;
        for (u32 k=0;k<c;k++){
          u8 st = sstat[cl[k]];
          if (st==1){ supp=true; break; }
          if (st==0) blocked=true;
        }
      }
      if (supp) sstat[r]=2;
      else if (!blocked) sstat[r]=1;
      else { u32 w=atomicAdd(&wcnt[nx],1u); wl[nx][w]=(u16)r; }
    }
    __syncthreads();
    if (t==0) wcnt[cur]=0;
    cur = nx;
    __syncthreads();
  }

  if (t < 256){
    u32 w = 0;
    for (int bi2=0;bi2<32;bi2++){
      int r = t*32+bi2;
      if (sstat[r]==1){
        u32 p = sp[r];
        u32 y=p>>16, x=p&0xFFFFu;
        if (x>=4 && x<HM_W-4 && y>=4 && y<HM_H-4) w |= (1u<<bi2);
      }
    }
    wpass[t]=w;
    wpre[t]=__popc(w);
  }
  __syncthreads();
  for (int off=1; off<256; off<<=1){
    u32 add = 0;
    if (t<256 && t>=off) add = wpre[t-off];
    __syncthreads();
    if (t<256) wpre[t] += add;
    __syncthreads();
  }
  u32 P = wpre[255];
  for (int r=t;r<CAND;r+=1024){
    u32 word = wpass[r>>5];
    u32 bit = (u32)r & 31u;
    bool pass = (word>>bit)&1u;
    u32 prank = ((r>>5)>0 ? wpre[(r>>5)-1] : 0u) + __popc(word & ((1u<<bit)-1u));
    u32 p = sp[r];
    u32 y,x;
    if (p==0xFFFFFFFFu){ y=HM_H-1; x=HM_W-1; } else { y=p>>16; x=p&0xFFFFu; }
    if (pass){
      if (prank < KPT) sel[b*KPT+prank] = (y<<16)|x;
    } else {
      u32 frank = (u32)r - prank;
      u32 slot = P + frank;
      if (slot < KPT) sel[b*KPT+slot] = (y<<16)|x;
    }
  }
}

__global__ void k_refine(const u32* __restrict__ sel, const float* __restrict__ hm,
                         const float* __restrict__ temp, float* __restrict__ pts){
  int t = blockIdx.x*256 + threadIdx.x;
  if (t >= BATCH*KPT) return;
  int b = t >> 10;
  u32 p = sel[t];
  int y = (int)(p>>16), x = (int)(p & 0xFFFFu);
  float T = temp[0];
  const float* hb = hm + (size_t)b*HM_N;
  float r[25]; float m = -3.0e38f;
  #pragma unroll
  for (int i=0;i<25;i++){
    int yy = y + (i%5) - 2;
    int xx = x + (i/5) - 2;
    if (yy<0) yy += HM_H; if (yy<0) yy=0; if (yy>HM_H-1) yy=HM_H-1;
    if (xx<0) xx += HM_W; if (xx<0) xx=0; if (xx>HM_W-1) xx=HM_W-1;
    float v = hb[yy*HM_W+xx] * T;
    r[i]=v; m=fmaxf(m,v);
  }
  float s=0.f, dy=0.f, dx=0.f;
  #pragma unroll
  for (int i=0;i<25;i++){
    float e = expf(r[i]-m);
    s += e;
    dy += e * (float)((i%5)-2);
    dx += e * (float)((i/5)-2);
  }
  dy /= s; dx /= s;
  pts[t*2+0] = (float)x + dx;
  pts[t*2+1] = (float)y + dy;
}

/* desc stage 1: block per (b,c); full channel plane in LDS; taps from LDS */
__global__ __launch_bounds__(256) void k_desc1(const float* __restrict__ pts, const float* __restrict__ cd,
                                               float* __restrict__ desc){
  extern __shared__ float plane[];   /* 19200 f32 */
  int blk = blockIdx.x;
  int b = blk >> 8;
  const float4* s4 = (const float4*)(cd + (size_t)blk*NCELL);
  float4* p4 = (float4*)plane;
  for (int i=threadIdx.x; i<NCELL/4; i+=256) p4[i]=s4[i];
  __syncthreads();
  for (int n=threadIdx.x; n<KPT; n+=256){
    float xf = pts[(b*KPT+n)*2+0], yf = pts[(b*KPT+n)*2+1];
    float gx = xf/640.0f - 1.0f;
    float gy = yf/480.0f - 1.0f;
    float ix = (gx+1.0f)*80.0f - 0.5f;
    float iy = (gy+1.0f)*60.0f - 0.5f;
    float x0f = floorf(ix), y0f = floorf(iy);
    float wx1 = ix-x0f, wy1 = iy-y0f;
    int x0=(int)x0f, y0=(int)y0f;
    bool xi0 = (x0>=0)&&(x0<160), xi1 = (x0+1>=0)&&(x0+1<160);
    bool yi0 = (y0>=0)&&(y0<120), yi1 = (y0+1>=0)&&(y0+1<120);
    int xc0 = min(max(x0,0),159),   xc1 = min(max(x0+1,0),159);
    int yc0 = min(max(y0,0),119),   yc1 = min(max(y0+1,0),119);
    float v00 = (xi0&&yi0) ? plane[yc0*160+xc0] : 0.f;
    float v01 = (xi1&&yi0) ? plane[yc0*160+xc1] : 0.f;
    float v10 = (xi0&&yi1) ? plane[yc1*160+xc0] : 0.f;
    float v11 = (xi1&&yi1) ? plane[yc1*160+xc1] : 0.f;
    float out = v00*(1.f-wx1)*(1.f-wy1) + v01*wx1*(1.f-wy1)
              + v10*(1.f-wx1)*wy1      + v11*wx1*wy1;
    desc[(size_t)blk*KPT + n] = out;
  }
}

/* desc stage 2: deterministic cross-channel norm + in-place normalize */
#define DN_T 32
__global__ __launch_bounds__(256) void k_dnorm(float* __restrict__ desc){
  __shared__ float tile[256*DN_T];
  __shared__ float part[8*DN_T];
  __shared__ float nrm[DN_T];
  int b = blockIdx.x >> 5;
  int n0 = (blockIdx.x & 31)*DN_T;
  int t = threadIdx.x;
  float* db = desc + (size_t)b*256*KPT + n0;
  for (int k=0;k<8;k++){
    int idx = t + 256*k;
    int c = idx >> 3, f4 = idx & 7;
    float4 v = *reinterpret_cast<const float4*>(db + (size_t)c*KPT + f4*4);
    *reinterpret_cast<float4*>(&tile[c*DN_T + f4*4]) = v;
  }
  __syncthreads();
  {
    int n = t & (DN_T-1), q = t >> 5;
    float s = 0.f;
    #pragma unroll
    for (int k=0;k<32;k++){
      float v = tile[(q+8*k)*DN_T + n];
      s += v*v;
    }
    part[q*DN_T + n] = s;
  }
  __syncthreads();
  if (t < DN_T){
    float tot = 0.f;
    #pragma unroll
    for (int q=0;q<8;q++) tot += part[q*DN_T + t];
    nrm[t] = fmaxf(sqrtf(tot), 1e-12f);
  }
  __syncthreads();
  for (int k=0;k<8;k++){
    int idx = t + 256*k;
    int c = idx >> 3, f4 = idx & 7;
    float4 v = *reinterpret_cast<const float4*>(&tile[c*DN_T + f4*4]);
    v.x /= nrm[f4*4+0]; v.y /= nrm[f4*4+1]; v.z /= nrm[f4*4+2]; v.w /= nrm[f4*4+3];
    *reinterpret_cast<float4*>(db + (size_t)c*KPT + f4*4) = v;
  }
}

extern "C" void kernel_launch(void* const* d_in, const int* in_sizes, int n_in,
                              void* d_out, int out_size, void* d_ws, size_t ws_size,
                              hipStream_t stream){
  const float* semi = (const float*)d_in[0];
  const float* cdsc = (const float*)d_in[1];
  const float* temp = (const float*)d_in[2];
  float* pts  = (float*)d_out;
  float* desc = pts + 4*1024*2;
  float* hm   = desc + (size_t)4*256*1024;
  char* ws = (char*)d_ws;
  u32* hist  = (u32*)(ws + WS_HIST);
  u32* meta  = (u32*)(ws + WS_META);
  u64* cand  = (u64*)(ws + WS_CAND);
  u64* eqk   = (u64*)(ws + WS_EQ);
  u32* sel   = (u32*)(ws + WS_SEL);
  float*  cm = (float*)(ws + WS_CM);
  double* cs = (double*)(ws + WS_CS);
  u32* spot  = (u32*)(ws + WS_SPOT);
  u32* bstG  = (u32*)(ws + WS_BST);
  u16* blistG= (u16*)(ws + WS_BLST);
  u32* cntG  = (u32*)(ws + WS_CNT);
  u8*  statG = (u8*)(ws + WS_STAT);
  u16* clistG= (u16*)(ws + WS_CLST);
  u64* cand2 = (u64*)(ws + WS_CAND2);

  hipMemsetAsync(ws, 0, WS_CAND, stream);

  hipFuncSetAttribute((const void*)k_heatmap, hipFuncAttributeMaxDynamicSharedMemorySize, NB20*4);
  k_heatmap<<<2400, 256, NB20*4, stream>>>(semi, hm, cm, cs, hist);
  k_reduce <<<4, 1024, 0, stream>>>(hist, meta);
  k_compact<<<1024, 256, 0, stream>>>(hm, meta, cand, eqk);
  k_eqprep <<<4, 256, 0, stream>>>(meta, cand, eqk, semi, cm, cs);
  k_sortloc<<<16, 512, 0, stream>>>(cand);
  k_merge  <<<128, 256, 0, stream>>>(cand, cand2, 2048);
  k_merge  <<<128, 256, 0, stream>>>(cand2, cand, 4096);
  hipFuncSetAttribute((const void*)k_sortfix, hipFuncAttributeMaxDynamicSharedMemorySize, CAND*8);
  k_sortfix<<<4, 1024, CAND*8, stream>>>(cand, semi, cm, cs, spot, bstG, blistG);
  k_nconf  <<<128, 256, 0, stream>>>(spot, bstG, blistG, cntG, statG, clistG);
  k_nresolve<<<4, 1024, 0, stream>>>(spot, bstG, blistG, cntG, statG, clistG, sel);
  k_refine <<<16, 256, 0, stream>>>(sel, hm, temp, pts);
  hipFuncSetAttribute((const void*)k_desc1, hipFuncAttributeMaxDynamicSharedMemorySize, NCELL*4);
  k_desc1  <<<1024, 256, NCELL*4, stream>>>(pts, cdsc, desc);
  k_dnorm  <<<128, 256, 0, stream>>>(desc);
}

// Round 15
// 199.419 us; speedup vs baseline: 1.0973x; 1.0973x over previous
//
#include <hip/hip_runtime.h>
#include <cstdint>

typedef unsigned int u32;
typedef unsigned long long u64;
typedef unsigned short u16;
typedef unsigned char u8;

#define HM_H 960
#define HM_W 1280
#define HM_N (HM_H*HM_W)       /* 1228800 */
#define BATCH 4
#define CAND 8192
#define KPT 1024
#define NCELL 19200            /* 120*160 */

/* workspace layout (bytes) */
#define WS_HISTA 0x0
#define WS_HISTB 0x100000
#define WS_META  0x200000      /* 4*64 u32 */
#define WS_CAND  0x200400      /* 4*8192 u64 */
#define WS_EQ    0x240400      /* 4*8192 u32 */
#define WS_SEL   0x280400      /* 4*1024 u32 */
#define WS_CM    0x284400      /* 4*19200 f32 */
#define WS_CS    0x2CF400      /* 4*19200 f64 */
#define WS_SPOT  0x365400      /* 4*8192 u32 packed (y<<16|x) */
#define WS_BST   0x385400      /* 4*4804 u32 bucket CSR starts */
#define WS_BLST  0x398040      /* 4*8192 u16 bucket entries (rank) */
#define WS_CNT   0x3A8040      /* 4*8192 u32 conflict count */
#define WS_STAT  0x3C8040      /* 4*8192 u8 status */
#define WS_CLST  0x3D0040      /* 4*8192*12 u16 conflict lists -> 0x4D0040 */
#define WS_CAND2 0x4D0040      /* 4*8192 u64 merge ping-pong */

/* meta fields per batch (stride 64 u32):
   0 pivotA, 1 needB, 2 countAboveA, 3 V32, 4 countGt, 5 needEq, 6 gtCtr, 7 eqCtr */

#define HBIN0 0x3C75u
#define NHBIN 780

__device__ inline double pixval64(const float* __restrict__ semi, const float* __restrict__ cm,
                                  const double* __restrict__ cs, int b, u32 idx){
  u32 y = idx / HM_W, x = idx - y*HM_W;
  u32 hc = y>>3, wc = x>>3, ch = ((y&7)<<3) | (x&7);
  float logit = semi[(((size_t)b*65 + ch)*120 + hc)*160 + wc];
  int cid = b*NCELL + (int)(hc*160 + wc);
  return exp((double)logit - (double)cm[cid]) / cs[cid];
}

/* 8-threads-per-cell softmax+depth2space + fused 16-bit histogram.
   LANE REMAP vs earlier: sub = lane>>3, cellLocal = lane&7, so each 8-lane
   group (fixed sub, 8 consecutive cells) writes one CONTIGUOUS 256B row
   segment (fixes the 2.4x write amplification seen in R14's counters).
   Cross-sub reductions use shfl_xor(8,16,32): identical pairing tree over
   subs as the old shfl_xor(1,2,4) => cm/cs/hm bit-identical. */
__global__ __launch_bounds__(256) void k_heatmap(const float* __restrict__ semi, float* __restrict__ hm,
                          float* __restrict__ cm, double* __restrict__ cs, u32* __restrict__ hist){
  __shared__ u32 lh[NHBIN];
  for (int i=threadIdx.x;i<NHBIN;i+=256) lh[i]=0;
  __syncthreads();
  const u32 FLOOR = 0x3C75C28Fu;
  int tid = blockIdx.x*256 + threadIdx.x;
  int lane = threadIdx.x & 63;
  int sub = lane >> 3;
  int cell = (tid >> 6)*8 + (lane & 7);   /* 8 cells per wave, consecutive */
  int wc = cell % 160; int hc = (cell/160) % 120; int b = cell / NCELL;
  const float* p = semi + (size_t)b*65*NCELL + hc*160 + wc;
  float r[8];
  #pragma unroll
  for (int i=0;i<8;i++) r[i] = p[(size_t)(sub*8+i)*NCELL];
  float extra = (sub==7) ? p[(size_t)64*NCELL] : -3.0e38f;
  float m = extra;
  #pragma unroll
  for (int i=0;i<8;i++) m = fmaxf(m, r[i]);
  m = fmaxf(m, __shfl_xor(m,8,64));
  m = fmaxf(m, __shfl_xor(m,16,64));
  m = fmaxf(m, __shfl_xor(m,32,64));
  double S = 0.0;
  #pragma unroll
  for (int i=0;i<8;i++) S += exp((double)r[i] - (double)m);
  if (sub==7) S += exp((double)extra - (double)m);
  S += __shfl_xor(S,8,64);
  S += __shfl_xor(S,16,64);
  S += __shfl_xor(S,32,64);
  if (sub==0){ cm[cell]=m; cs[cell]=S; }
  float* out = hm + ((size_t)b*HM_H + hc*8 + sub)*HM_W + wc*8;
  float o[8];
  #pragma unroll
  for (int i=0;i<8;i++) o[i] = (float)(exp((double)r[i] - (double)m) / S);
  *reinterpret_cast<float4*>(out)     = make_float4(o[0],o[1],o[2],o[3]);
  *reinterpret_cast<float4*>(out + 4) = make_float4(o[4],o[5],o[6],o[7]);
  #pragma unroll
  for (int i=0;i<8;i++){
    u32 bs = __float_as_uint(o[i]);
    if (bs>=FLOOR){ u32 bi=(bs>>16)-HBIN0; if(bi>=NHBIN)bi=NHBIN-1; atomicAdd(&lh[bi],1u); }
  }
  __syncthreads();
  int bblk = blockIdx.x / 600;            /* 600 blocks per batch exactly */
  u32* h = hist + bblk*65536 + HBIN0;
  for (int i=threadIdx.x;i<NHBIN;i+=256){
    u32 c=lh[i]; if (c) atomicAdd(&h[i], c);
  }
}

/* chunked histB: batch-uniform blocks, contiguous float4, sparse global atomics */
__global__ __launch_bounds__(256) void k_histB(const float* __restrict__ hm, const u32* __restrict__ meta,
                                               u32* __restrict__ hist){
  const u32 FLOOR = 0x3C75C28Fu;
  int b = blockIdx.x >> 8;
  int chunk = blockIdx.x & 255;
  u32 piv = meta[b*64+0];
  u32* h = hist + b*65536;
  const float4* src = (const float4*)(hm + (size_t)b*HM_N);
  int per = (HM_N/4)/256;
  int start = chunk*per;
  for (int i=start+(int)threadIdx.x; i<start+per; i+=256){
    float4 v = src[i];
    u32 bs;
    bs = __float_as_uint(v.x); if (bs >= FLOOR && (bs>>16)==piv) atomicAdd(&h[bs & 0xFFFFu], 1u);
    bs = __float_as_uint(v.y); if (bs >= FLOOR && (bs>>16)==piv) atomicAdd(&h[bs & 0xFFFFu], 1u);
    bs = __float_as_uint(v.z); if (bs >= FLOOR && (bs>>16)==piv) atomicAdd(&h[bs & 0xFFFFu], 1u);
    bs = __float_as_uint(v.w); if (bs >= FLOOR && (bs>>16)==piv) atomicAdd(&h[bs & 0xFFFFu], 1u);
  }
}

__global__ void k_reduce(const u32* __restrict__ hist, u32* __restrict__ meta, int phase){
  int b = blockIdx.x;
  const u32* h = hist + b*65536;
  u32* mb = meta + b*64;
  u32 K = (phase==0) ? (u32)CAND : mb[1];
  int t = threadIdx.x;
  __shared__ u32 suf[1024];
  u32 s = 0;
  for (int i=0;i<64;i++) s += h[t*64+i];
  suf[t]=s; __syncthreads();
  for (int off=1; off<1024; off<<=1){
    u32 add = (t+off<1024) ? suf[t+off] : 0u;
    u32 nv2 = suf[t] + add;
    __syncthreads();
    suf[t]=nv2; __syncthreads();
  }
  u32 total = suf[0];
  u32 cumAbove = (t<1023) ? suf[t+1] : 0u;
  bool found = (cumAbove < K) && (cumAbove + s >= K);
  if (found){
    u32 cum = cumAbove; int bin = 0; u32 cA = cumAbove;
    for (int i=63;i>=0;i--){
      u32 c = h[t*64+i];
      if (cum + c >= K){ bin = t*64+i; cA = cum; break; }
      cum += c;
    }
    if (phase==0){ mb[0]=(u32)bin; mb[2]=cA; mb[1]=K-cA; }
    else {
      u32 V = (mb[0]<<16) | (u32)bin; mb[3]=V;
      u32 cg = mb[2] + cA; mb[4]=cg;
      mb[5] = (cg < (u32)CAND) ? ((u32)CAND - cg) : 0u;
    }
  }
  if (t==0 && total < K){
    if (phase==0){ mb[0]=0; mb[2]=total; mb[1]=K-total; }
    else {
      u32 V = (mb[0]<<16); mb[3]=V;
      u32 cg = mb[2] + total; mb[4]=cg;
      mb[5] = (cg < (u32)CAND) ? ((u32)CAND - cg) : 0u;
    }
  }
}

#define CB_CAP 4800
__global__ __launch_bounds__(256) void k_compact(const float* __restrict__ hm, u32* __restrict__ meta,
                          u64* __restrict__ cand, u32* __restrict__ eq){
  __shared__ u32 pixb[CB_CAP];
  __shared__ u32 bsb[CB_CAP];
  __shared__ u32 eqb[CB_CAP];
  __shared__ u32 cnt, ecnt, gbase, ebase;
  int b = blockIdx.x >> 8;
  int chunk = blockIdx.x & 255;
  if (threadIdx.x==0){ cnt=0u; ecnt=0u; }
  __syncthreads();
  u32 V = meta[b*64+3];
  const float4* src = (const float4*)(hm + (size_t)b*HM_N);
  int per = (HM_N/4)/256;
  int start = chunk*per;
  for (int i=start+(int)threadIdx.x; i<start+per; i+=256){
    float4 v = src[i];
    u32 pix = (u32)i*4u;
    u32 bs4[4];
    bs4[0]=__float_as_uint(v.x); bs4[1]=__float_as_uint(v.y);
    bs4[2]=__float_as_uint(v.z); bs4[3]=__float_as_uint(v.w);
    #pragma unroll
    for (int c2=0;c2<4;c2++){
      u32 bs = bs4[c2];
      if (bs > V){ u32 p = atomicAdd(&cnt,1u); pixb[p]=pix+(u32)c2; bsb[p]=bs; }
      else if (bs == V){ u32 e = atomicAdd(&ecnt,1u); eqb[e]=pix+(u32)c2; }
    }
  }
  __syncthreads();
  if (threadIdx.x==0){
    gbase = cnt  ? atomicAdd(&meta[b*64+6], cnt)  : 0u;
    ebase = ecnt ? atomicAdd(&meta[b*64+7], ecnt) : 0u;
  }
  __syncthreads();
  u32 c0=cnt, e0=ecnt, gb=gbase, eb=ebase;
  for (u32 i=threadIdx.x; i<c0; i+=256){
    u32 s2 = gb+i;
    if (s2 < CAND) cand[(size_t)b*CAND+s2] = (((u64)(~bsb[i]))<<32)|(u64)pixb[i];
  }
  for (u32 i=threadIdx.x; i<e0; i+=256){
    u32 s2 = eb+i;
    if (s2 < CAND) eq[(size_t)b*CAND+s2] = eqb[i];
  }
}

__global__ void k_eqprep(const u32* __restrict__ meta, u64* __restrict__ cand, const u32* __restrict__ eq,
                         const float* __restrict__ semi, const float* __restrict__ cm,
                         const double* __restrict__ cs){
  int b = blockIdx.x;
  __shared__ double vv[64];
  __shared__ u32 ii[64];
  if (threadIdx.x != 0) return;
  const u32* mb = meta + b*64;
  u32 countGt = mb[4], needEq = mb[5], V32 = mb[3];
  int n = (int)mb[7]; if (n > 64) n = 64;
  for (int j=0;j<n;j++){
    ii[j] = eq[(size_t)b*CAND + j];
    vv[j] = pixval64(semi, cm, cs, b, ii[j]);
  }
  for (int j=1;j<n;j++){
    double vj = vv[j]; u32 ij = ii[j];
    int q = j-1;
    while (q >= 0 && (vv[q] < vj || (vv[q] == vj && ii[q] > ij))){
      vv[q+1]=vv[q]; ii[q+1]=ii[q]; q--;
    }
    vv[q+1]=vj; ii[q+1]=ij;
  }
  u64 vq = ((u64)(~V32))<<32;
  for (u32 r=0; r<needEq; r++){
    u64 key = (r < (u32)n) ? (vq | (u64)ii[r]) : ~0ull;
    if (countGt + r < CAND) cand[(size_t)b*CAND + countGt + r] = key;
  }
}

/* local bitonic sort of a 2048-key segment (16 blocks = 4 batch x 4 seg). */
__global__ __launch_bounds__(512,1) void k_sortloc(u64* __restrict__ cand){
  __shared__ u64 sk[2048];
  int blk = blockIdx.x;
  int b = blk >> 2, seg = blk & 3;
  int t = threadIdx.x;
  int lane = t & 63, w = t >> 6;
  int base = w*256 + lane;
  u64* cb = cand + (size_t)b*CAND + seg*2048;
  u64 E[4];
  #pragma unroll
  for (int m=0;m<4;m++) E[m] = cb[base + m*64];

  for (int k2=2; k2<=2048; k2<<=1){
    int j = k2>>1;
    if (j >= 256){
      __syncthreads();
      #pragma unroll
      for (int m=0;m<4;m++) sk[base + m*64] = E[m];
      __syncthreads();
      for (; j>=256; j>>=1){
        int lj = __ffs(j)-1;
        for (int p=t; p<1024; p+=512){
          int i = ((p >> lj) << (lj+1)) | (p & (j-1));
          int l = i | j;
          bool up = ((i & k2)==0);
          u64 a=sk[i], c=sk[l];
          if ((a>c)==up){ sk[i]=c; sk[l]=a; }
        }
        __syncthreads();
      }
      #pragma unroll
      for (int m=0;m<4;m++) E[m] = sk[base + m*64];
      j = 128;
    }
    for (; j>=64; j>>=1){
      int mm = j>>6;
      #pragma unroll
      for (int m=0;m<4;m++){
        if ((m & mm)==0){
          int i = base + m*64;
          bool up = ((i & k2)==0);
          u64 a=E[m], c=E[m|mm];
          if ((a>c)==up){ E[m]=c; E[m|mm]=a; }
        }
      }
    }
    for (; j>=1; j>>=1){
      bool low0 = ((lane & j)==0);
      #pragma unroll
      for (int m=0;m<4;m++){
        int i = base + m*64;
        bool up = ((i & k2)==0);
        bool keepmin = (low0==up);
        u64 P = (u64)__shfl_xor((long long)E[m], j, 64);
        u64 mn = E[m]<P ? E[m] : P;
        u64 mx = E[m]<P ? P : E[m];
        E[m] = keepmin ? mn : mx;
      }
    }
  }
  #pragma unroll
  for (int m=0;m<4;m++) cb[base + m*64] = E[m];
}

/* stable parallel merge of sorted runs L -> 2L (merge-path, whole chip). */
__global__ __launch_bounds__(256) void k_merge(const u64* __restrict__ src, u64* __restrict__ dst, int L){
  int tid = blockIdx.x*256 + (int)threadIdx.x;
  if (tid >= BATCH*CAND) return;
  int b = tid >> 13;
  int e = tid & (CAND-1);
  int pairBase = (e / (2*L)) * (2*L);
  int off = e - pairBase;
  const u64* A = src + ((size_t)b<<13) + pairBase;
  const u64* B = A + L;
  bool inA = off < L;
  int i = inA ? off : off - L;
  u64 key = inA ? A[i] : B[i];
  const u64* O = inA ? B : A;
  int lo = 0, hi = L;
  if (inA){
    while (lo < hi){ int mid=(lo+hi)>>1; if (O[mid] < key) lo=mid+1; else hi=mid; }
  } else {
    while (lo < hi){ int mid=(lo+hi)>>1; if (O[mid] <= key) lo=mid+1; else hi=mid; }
  }
  dst[((size_t)b<<13) + pairBase + i + lo] = key;
}

/* f64 tie-cleanup + FUSED NMS stage 1 (spot + bucket CSR) from LDS. */
#define NBX 80
#define NBY 60
#define NBK (NBX*NBY)
#define BSTSTRIDE 4804
__global__ __launch_bounds__(1024,1) void k_sortfix(const u64* __restrict__ cand,
                       const float* __restrict__ semi, const float* __restrict__ cm,
                       const double* __restrict__ cs,
                       u32* __restrict__ spot, u32* __restrict__ bstG, u16* __restrict__ blistG){
  __shared__ u32 bcnt[NBK];
  __shared__ u32 bst[NBK];
  __shared__ u32 tsum[1024];
  extern __shared__ u64 sk[];
  int b = blockIdx.x, t = threadIdx.x;
  const u64* cb = cand + (size_t)b*CAND;
  for (int i=t;i<CAND;i+=1024) sk[i]=cb[i];
  for (int i=t;i<NBK;i+=1024) bcnt[i]=0;
  __syncthreads();
  for (int pass=0; pass<8; pass++){
    int par = pass & 1;
    for (int q=t; q<CAND/2; q+=1024){
      int p = par + 2*q;
      if (p+1 < CAND){
        u64 a = sk[p], c = sk[p+1];
        u32 ha = (u32)(a>>32), hc2 = (u32)(c>>32);
        if (ha == hc2 && ha != 0xFFFFFFFFu){
          double va = pixval64(semi, cm, cs, b, (u32)a);
          double vc = pixval64(semi, cm, cs, b, (u32)c);
          if (va < vc || (va == vc && (u32)a > (u32)c)){ sk[p]=c; sk[p+1]=a; }
        }
      }
    }
    __syncthreads();
  }
  for (int r=t;r<CAND;r+=1024){
    u32 idx = (u32)sk[r];
    u32 p;
    if (idx != 0xFFFFFFFFu){
      u32 y = idx/HM_W, x = idx - y*HM_W;
      p = (y<<16)|x;
      atomicAdd(&bcnt[(y>>4)*NBX+(x>>4)], 1u);
    } else p = 0xFFFFFFFFu;
    spot[(size_t)b*CAND+r] = p;
  }
  __syncthreads();
  u32 lsum=0;
  int base5 = t*5;
  if (base5 < NBK){
    #pragma unroll
    for (int j2=0;j2<5;j2++){ int ix=base5+j2; if (ix<NBK) lsum += bcnt[ix]; }
  }
  tsum[t]=lsum;
  __syncthreads();
  for (int off=1; off<1024; off<<=1){
    u32 add = (t>=off)? tsum[t-off] : 0u;
    __syncthreads();
    tsum[t] += add;
    __syncthreads();
  }
  if (base5 < NBK){
    u32 run = (t==0)?0u:tsum[t-1];
    #pragma unroll
    for (int j2=0;j2<5;j2++){
      int ix=base5+j2; if (ix<NBK){ u32 c=bcnt[ix]; bst[ix]=run; run+=c; }
    }
  }
  __syncthreads();
  for (int i=t;i<NBK;i+=1024){ bcnt[i]=bst[i]; bstG[(size_t)b*BSTSTRIDE+i]=bst[i]; }
  if (t==0) bstG[(size_t)b*BSTSTRIDE+NBK] = tsum[1023];
  __syncthreads();
  for (int r=t;r<CAND;r+=1024){
    u32 idx = (u32)sk[r];
    if (idx != 0xFFFFFFFFu){
      u32 y = idx/HM_W, x = idx - y*HM_W;
      u32 bu = (y>>4)*NBX + (x>>4);
      u32 slot = atomicAdd(&bcnt[bu],1u);
      blistG[(size_t)b*CAND+slot] = (u16)r;
    }
  }
}

/* NMS stage 2: per-candidate earlier-rank conflict lists (whole chip) */
#define CLCAP 12
__global__ __launch_bounds__(256) void k_nconf(const u32* __restrict__ spot, const u32* __restrict__ bstG,
                                               const u16* __restrict__ blistG, u32* __restrict__ cntG,
                                               u8* __restrict__ statG, u16* __restrict__ clistG){
  int b = blockIdx.x >> 5;
  int r = (blockIdx.x & 31)*256 + (int)threadIdx.x;
  const u32* sp = spot + (size_t)b*CAND;
  u32 p = sp[r];
  if (p == 0xFFFFFFFFu){ statG[(size_t)b*CAND+r]=2; return; }
  int y=(int)(p>>16), x=(int)(p&0xFFFFu);
  int by=y>>4, bx=x>>4;
  const u32* bs = bstG + (size_t)b*BSTSTRIDE;
  const u16* bl = blistG + (size_t)b*CAND;
  u16* cl = clistG + ((size_t)b*CAND + r)*CLCAP;
  int cnt=0; bool heavy=false;
  for (int dy=-1; dy<=1; dy++){
    int yy=by+dy; if (yy<0||yy>=NBY) continue;
    for (int dx=-1; dx<=1; dx++){
      int xx=bx+dx; if (xx<0||xx>=NBX) continue;
      int bu=yy*NBX+xx;
      int s=(int)bs[bu], e=(int)bs[bu+1];
      for (int q=s;q<e;q++){
        int j = (int)bl[q];
        if (j >= r) continue;
        u32 pj = sp[j];
        int ady = y-(int)(pj>>16); ady = ady<0?-ady:ady;
        int adx = x-(int)(pj&0xFFFFu); adx = adx<0?-adx:adx;
        if (ady<=4 && adx<=4){
          if (cnt < CLCAP) cl[cnt++] = (u16)j;
          else heavy = true;
        }
      }
    }
  }
  if (heavy){ cntG[(size_t)b*CAND+r]=0xFFFFFFFFu; statG[(size_t)b*CAND+r]=0; }
  else { cntG[(size_t)b*CAND+r]=(u32)cnt; statG[(size_t)b*CAND+r] = (cnt==0)?1:0; }
}

/* NMS stage 3: worklist fixed point + selection */
__global__ __launch_bounds__(1024,1) void k_nresolve(const u32* __restrict__ spot, const u32* __restrict__ bstG,
                                                     const u16* __restrict__ blistG, const u32* __restrict__ cntG,
                                                     u8* __restrict__ statG, const u16* __restrict__ clistG,
                                                     u32* __restrict__ sel){
  __shared__ u8 sstat[CAND];
  __shared__ u16 wl[2][CAND];
  __shared__ u32 wcnt[2];
  __shared__ u32 wpass[256];
  __shared__ u32 wpre[256];
  int b = blockIdx.x, t = threadIdx.x;
  const u32* sp = spot + (size_t)b*CAND;
  if (t<2) wcnt[t]=0;
  __syncthreads();
  for (int r=t;r<CAND;r+=1024){
    u8 st = statG[(size_t)b*CAND+r];
    sstat[r]=st;
    if (st==0){ u32 w=atomicAdd(&wcnt[0],1u); wl[0][w]=(u16)r; }
  }
  __syncthreads();
  int cur=0;
  for (int round=0; round<8192; ++round){
    int n = (int)wcnt[cur];
    if (n==0) break;
    int nx = cur^1;
    for (int i=t;i<n;i+=1024){
      int r = (int)wl[cur][i];
      u32 c = cntG[(size_t)b*CAND+r];
      bool supp=false, blocked=false;
      if (c==0xFFFFFFFFu){
        u32 p = sp[r];
        int y=(int)(p>>16), x=(int)(p&0xFFFFu);
        int by=y>>4, bx=x>>4;
        const u32* bs = bstG + (size_t)b*BSTSTRIDE;
        const u16* bl = blistG + (size_t)b*CAND;
        for (int dy=-1; dy<=1 && !supp; dy++){
          int yy=by+dy; if (yy<0||yy>=NBY) continue;
          for (int dx=-1; dx<=1 && !supp; dx++){
            int xx=bx+dx; if (xx<0||xx>=NBX) continue;
            int bu=yy*NBX+xx;
            int s=(int)bs[bu], e=(int)bs[bu+1];
            for (int q=s;q<e;q++){
              int j = (int)bl[q];
              if (j >= r) continue;
              u32 pj = sp[j];
              int ady = y-(int)(pj>>16); ady = ady<0?-ady:ady;
              int adx = x-(int)(pj&0xFFFFu); adx = adx<0?-adx:adx;
              if (ady<=4 && adx<=4){
                u8 st = sstat[j];
                if (st==1){ supp=true; break; }
                if (st==0) blocked=true;
              }
            }
          }
        }
      } else {
        const u16* cl = clistG + ((size_t)b*CAND + r)*CLCAP;
        for (u32 k=0;k<c;k++){
          u8 st = sstat[cl[k]];
          if (st==1){ supp=true; break; }
          if (st==0) blocked=true;
        }
      }
      if (supp) sstat[r]=2;
      else if (!blocked) sstat[r]=1;
      else { u32 w=atomicAdd(&wcnt[nx],1u); wl[nx][w]=(u16)r; }
    }
    __syncthreads();
    if (t==0) wcnt[cur]=0;
    cur = nx;
    __syncthreads();
  }

  if (t < 256){
    u32 w = 0;
    for (int bi2=0;bi2<32;bi2++){
      int r = t*32+bi2;
      if (sstat[r]==1){
        u32 p = sp[r];
        u32 y=p>>16, x=p&0xFFFFu;
        if (x>=4 && x<HM_W-4 && y>=4 && y<HM_H-4) w |= (1u<<bi2);
      }
    }
    wpass[t]=w;
    wpre[t]=__popc(w);
  }
  __syncthreads();
  for (int off=1; off<256; off<<=1){
    u32 add = 0;
    if (t<256 && t>=off) add = wpre[t-off];
    __syncthreads();
    if (t<256) wpre[t] += add;
    __syncthreads();
  }
  u32 P = wpre[255];
  for (int r=t;r<CAND;r+=1024){
    u32 word = wpass[r>>5];
    u32 bit = (u32)r & 31u;
    bool pass = (word>>bit)&1u;
    u32 prank = ((r>>5)>0 ? wpre[(r>>5)-1] : 0u) + __popc(word & ((1u<<bit)-1u));
    u32 p = sp[r];
    u32 y,x;
    if (p==0xFFFFFFFFu){ y=HM_H-1; x=HM_W-1; } else { y=p>>16; x=p&0xFFFFu; }
    if (pass){
      if (prank < KPT) sel[b*KPT+prank] = (y<<16)|x;
    } else {
      u32 frank = (u32)r - prank;
      u32 slot = P + frank;
      if (slot < KPT) sel[b*KPT+slot] = (y<<16)|x;
    }
  }
}

__global__ void k_refine(const u32* __restrict__ sel, const float* __restrict__ hm,
                         const float* __restrict__ temp, float* __restrict__ pts){
  int t = blockIdx.x*256 + threadIdx.x;
  if (t >= BATCH*KPT) return;
  int b = t >> 10;
  u32 p = sel[t];
  int y = (int)(p>>16), x = (int)(p & 0xFFFFu);
  float T = temp[0];
  const float* hb = hm + (size_t)b*HM_N;
  float r[25]; float m = -3.0e38f;
  #pragma unroll
  for (int i=0;i<25;i++){
    int yy = y + (i%5) - 2;
    int xx = x + (i/5) - 2;
    if (yy<0) yy += HM_H; if (yy<0) yy=0; if (yy>HM_H-1) yy=HM_H-1;
    if (xx<0) xx += HM_W; if (xx<0) xx=0; if (xx>HM_W-1) xx=HM_W-1;
    float v = hb[yy*HM_W+xx] * T;
    r[i]=v; m=fmaxf(m,v);
  }
  float s=0.f, dy=0.f, dx=0.f;
  #pragma unroll
  for (int i=0;i<25;i++){
    float e = expf(r[i]-m);
    s += e;
    dy += e * (float)((i%5)-2);
    dx += e * (float)((i/5)-2);
  }
  dy /= s; dx /= s;
  pts[t*2+0] = (float)x + dx;
  pts[t*2+1] = (float)y + dy;
}

/* desc stage 1: block per (b,c); full channel plane in LDS; taps from LDS */
__global__ __launch_bounds__(256) void k_desc1(const float* __restrict__ pts, const float* __restrict__ cd,
                                               float* __restrict__ desc){
  extern __shared__ float plane[];   /* 19200 f32 */
  int blk = blockIdx.x;
  int b = blk >> 8;
  const float4* s4 = (const float4*)(cd + (size_t)blk*NCELL);
  float4* p4 = (float4*)plane;
  for (int i=threadIdx.x; i<NCELL/4; i+=256) p4[i]=s4[i];
  __syncthreads();
  for (int n=threadIdx.x; n<KPT; n+=256){
    float xf = pts[(b*KPT+n)*2+0], yf = pts[(b*KPT+n)*2+1];
    float gx = xf/640.0f - 1.0f;
    float gy = yf/480.0f - 1.0f;
    float ix = (gx+1.0f)*80.0f - 0.5f;
    float iy = (gy+1.0f)*60.0f - 0.5f;
    float x0f = floorf(ix), y0f = floorf(iy);
    float wx1 = ix-x0f, wy1 = iy-y0f;
    int x0=(int)x0f, y0=(int)y0f;
    bool xi0 = (x0>=0)&&(x0<160), xi1 = (x0+1>=0)&&(x0+1<160);
    bool yi0 = (y0>=0)&&(y0<120), yi1 = (y0+1>=0)&&(y0+1<120);
    int xc0 = min(max(x0,0),159),   xc1 = min(max(x0+1,0),159);
    int yc0 = min(max(y0,0),119),   yc1 = min(max(y0+1,0),119);
    float v00 = (xi0&&yi0) ? plane[yc0*160+xc0] : 0.f;
    float v01 = (xi1&&yi0) ? plane[yc0*160+xc1] : 0.f;
    float v10 = (xi0&&yi1) ? plane[yc1*160+xc0] : 0.f;
    float v11 = (xi1&&yi1) ? plane[yc1*160+xc1] : 0.f;
    float out = v00*(1.f-wx1)*(1.f-wy1) + v01*wx1*(1.f-wy1)
              + v10*(1.f-wx1)*wy1      + v11*wx1*wy1;
    desc[(size_t)blk*KPT + n] = out;
  }
}

/* desc stage 2: deterministic cross-channel norm + in-place normalize */
#define DN_T 32
__global__ __launch_bounds__(256) void k_dnorm(float* __restrict__ desc){
  __shared__ float tile[256*DN_T];
  __shared__ float part[8*DN_T];
  __shared__ float nrm[DN_T];
  int b = blockIdx.x >> 5;
  int n0 = (blockIdx.x & 31)*DN_T;
  int t = threadIdx.x;
  float* db = desc + (size_t)b*256*KPT + n0;
  for (int k=0;k<8;k++){
    int idx = t + 256*k;
    int c = idx >> 3, f4 = idx & 7;
    float4 v = *reinterpret_cast<const float4*>(db + (size_t)c*KPT + f4*4);
    *reinterpret_cast<float4*>(&tile[c*DN_T + f4*4]) = v;
  }
  __syncthreads();
  {
    int n = t & (DN_T-1), q = t >> 5;
    float s = 0.f;
    #pragma unroll
    for (int k=0;k<32;k++){
      float v = tile[(q+8*k)*DN_T + n];
      s += v*v;
    }
    part[q*DN_T + n] = s;
  }
  __syncthreads();
  if (t < DN_T){
    float tot = 0.f;
    #pragma unroll
    for (int q=0;q<8;q++) tot += part[q*DN_T + t];
    nrm[t] = fmaxf(sqrtf(tot), 1e-12f);
  }
  __syncthreads();
  for (int k=0;k<8;k++){
    int idx = t + 256*k;
    int c = idx >> 3, f4 = idx & 7;
    float4 v = *reinterpret_cast<const float4*>(&tile[c*DN_T + f4*4]);
    v.x /= nrm[f4*4+0]; v.y /= nrm[f4*4+1]; v.z /= nrm[f4*4+2]; v.w /= nrm[f4*4+3];
    *reinterpret_cast<float4*>(db + (size_t)c*KPT + f4*4) = v;
  }
}

extern "C" void kernel_launch(void* const* d_in, const int* in_sizes, int n_in,
                              void* d_out, int out_size, void* d_ws, size_t ws_size,
                              hipStream_t stream){
  const float* semi = (const float*)d_in[0];
  const float* cdsc = (const float*)d_in[1];
  const float* temp = (const float*)d_in[2];
  float* pts  = (float*)d_out;
  float* desc = pts + 4*1024*2;
  float* hm   = desc + (size_t)4*256*1024;
  char* ws = (char*)d_ws;
  u32* histA = (u32*)(ws + WS_HISTA);
  u32* histB = (u32*)(ws + WS_HISTB);
  u32* meta  = (u32*)(ws + WS_META);
  u64* cand  = (u64*)(ws + WS_CAND);
  u32* eq    = (u32*)(ws + WS_EQ);
  u32* sel   = (u32*)(ws + WS_SEL);
  float*  cm = (float*)(ws + WS_CM);
  double* cs = (double*)(ws + WS_CS);
  u32* spot  = (u32*)(ws + WS_SPOT);
  u32* bstG  = (u32*)(ws + WS_BST);
  u16* blistG= (u16*)(ws + WS_BLST);
  u32* cntG  = (u32*)(ws + WS_CNT);
  u8*  statG = (u8*)(ws + WS_STAT);
  u16* clistG= (u16*)(ws + WS_CLST);
  u64* cand2 = (u64*)(ws + WS_CAND2);

  hipMemsetAsync(ws, 0, WS_CAND, stream);

  k_heatmap<<<2400, 256, 0, stream>>>(semi, hm, cm, cs, histA);
  k_reduce <<<4, 1024, 0, stream>>>(histA, meta, 0);
  k_histB  <<<1024, 256, 0, stream>>>(hm, meta, histB);
  k_reduce <<<4, 1024, 0, stream>>>(histB, meta, 1);
  k_compact<<<1024, 256, 0, stream>>>(hm, meta, cand, eq);
  k_eqprep <<<4, 64, 0, stream>>>(meta, cand, eq, semi, cm, cs);
  k_sortloc<<<16, 512, 0, stream>>>(cand);
  k_merge  <<<128, 256, 0, stream>>>(cand, cand2, 2048);
  k_merge  <<<128, 256, 0, stream>>>(cand2, cand, 4096);
  hipFuncSetAttribute((const void*)k_sortfix, hipFuncAttributeMaxDynamicSharedMemorySize, CAND*8);
  k_sortfix<<<4, 1024, CAND*8, stream>>>(cand, semi, cm, cs, spot, bstG, blistG);
  k_nconf  <<<128, 256, 0, stream>>>(spot, bstG, blistG, cntG, statG, clistG);
  k_nresolve<<<4, 1024, 0, stream>>>(spot, bstG, blistG, cntG, statG, clistG, sel);
  k_refine <<<16, 256, 0, stream>>>(sel, hm, temp, pts);
  hipFuncSetAttribute((const void*)k_desc1, hipFuncAttributeMaxDynamicSharedMemorySize, NCELL*4);
  k_desc1  <<<1024, 256, NCELL*4, stream>>>(pts, cdsc, desc);
  k_dnorm  <<<128, 256, 0, stream>>>(desc);
}